// Round 1
// baseline (1009.347 us; speedup 1.0000x reference)
//
#include <hip/hip_runtime.h>
#include <hip/hip_fp8.h>

#define N_NODES 50000
#define N_EDGES 800000
#define IN_C    128
#define HID_C   128
#define OUT_C   64

#define EPB     4096            // edges per scatter block
#define NBLK    196             // ceil(N_EDGES / EPB)
#define BSH     5               // bucket = dst >> 5  (32 nodes per bucket)
#define BSZ     32
#define NB      1563            // ceil(N_NODES / 32)
#define CAPB    768             // mean 512, sigma ~22.6 -> +11 sigma margin

typedef unsigned int       uint32;
typedef unsigned short     ushort16;
typedef unsigned char      uchar8;
typedef unsigned long long u64;
typedef __attribute__((ext_vector_type(8))) short short8;
typedef __attribute__((ext_vector_type(4))) float f32x4;

__device__ __forceinline__ ushort16 f2bf(float f) {
    uint32 u = __float_as_uint(f);
    u += 0x7FFFu + ((u >> 16) & 1u);        // RNE
    return (ushort16)(u >> 16);
}
__device__ __forceinline__ float bf_lo(uint32 h) { return __uint_as_float(h << 16); }
__device__ __forceinline__ float bf_hi(uint32 h) { return __uint_as_float(h & 0xFFFF0000u); }

__device__ __forceinline__ ushort16 f2h_bits(float f) {
    union { _Float16 h; ushort16 u; } cv;
    cv.h = (_Float16)f;
    return cv.u;
}
__device__ __forceinline__ float h_bits2f(uint32 bits) {
    union { ushort16 u; _Float16 h; } cv;
    cv.u = (ushort16)bits;
    return (float)cv.h;
}
__device__ __forceinline__ uchar8 f2fp8(float f) {
    __hip_fp8_e4m3 t(f);                    // OCP e4m3fn, RNE-saturating
    return *reinterpret_cast<unsigned char*>(&t);
}
__device__ __forceinline__ float fp82f(uchar8 b) {
    __hip_fp8_e4m3 t;
    *reinterpret_cast<unsigned char*>(&t) = b;
    return (float)t;
}

// ---- W pre-transpose (bf16) + bucket-cursor zeroing -------------------------
__global__ void prep_w_kernel(const float* __restrict__ W1, const float* __restrict__ W2,
                              ushort16* __restrict__ W1t, ushort16* __restrict__ W2t,
                              int* __restrict__ cursor) {
    if (blockIdx.x == 0) {
        for (int j = threadIdx.x; j < NB; j += 256) cursor[j] = 0;
    }
    int i = blockIdx.x * 256 + threadIdx.x;
    if (i < 128 * 128) {
        int n = i / 128, k = i % 128;
        W1t[i] = f2bf(W1[k * 128 + n]);
    }
    int j = i - 128 * 128;
    if (j >= 0 && j < 64 * 128) {
        int n = j / 128, k = j % 128;
        W2t[j] = f2bf(W2[k * 64 + n]);
    }
}

// ---------------- MFMA GEMM: C[M,N] = A[M,128] * W[128,N] --------------------
template<int NT, bool ABF16, bool OUTFP8>
__global__ __launch_bounds__(256) void mfma_gemm_kernel(const void* __restrict__ Aptr,
                                                        const ushort16* __restrict__ Wt,
                                                        void* __restrict__ Cout, int M) {
    constexpr int N = NT * 16;
    __shared__ ushort16 As[64][136];       // +8 pad breaks 16-way bank aliasing
    __shared__ ushort16 Ws[N][136];

    const int tid  = threadIdx.x;
    const int wave = tid >> 6;
    const int lane = tid & 63;
    const int quad = lane >> 4;
    const int m    = lane & 15;
    const int blockRow = blockIdx.x * 64;

#pragma unroll
    for (int p = 0; p < N * 16 / 256; p++) {
        int u = tid + 256 * p;
        int row = u / 16, c8 = u % 16;
        uint4 v = ((const uint4*)Wt)[u];
        *((uint4*)&Ws[row][c8 * 8]) = v;
    }
    if (ABF16) {
#pragma unroll
        for (int p = 0; p < 4; p++) {
            int u = tid + 256 * p;
            int row = u / 16, c8 = u % 16;
            int gr = blockRow + row; if (gr > M - 1) gr = M - 1;
            uint4 v = ((const uint4*)Aptr)[gr * 16 + c8];
            *((uint4*)&As[row][c8 * 8]) = v;
        }
    } else {
#pragma unroll
        for (int p = 0; p < 8; p++) {
            int u = tid + 256 * p;
            int row = u / 32, c4 = u % 32;
            int gr = blockRow + row; if (gr > M - 1) gr = M - 1;
            float4 v = ((const float4*)Aptr)[gr * 32 + c4];
            ushort4 s;
            s.x = f2bf(v.x); s.y = f2bf(v.y); s.z = f2bf(v.z); s.w = f2bf(v.w);
            *((ushort4*)&As[row][c4 * 4]) = s;
        }
    }
    __syncthreads();

    f32x4 acc[NT];
#pragma unroll
    for (int nt = 0; nt < NT; nt++) acc[nt] = (f32x4){0.f, 0.f, 0.f, 0.f};

#pragma unroll
    for (int kc = 0; kc < 128; kc += 32) {
        short8 a = *((const short8*)&As[wave * 16 + m][kc + quad * 8]);
#pragma unroll
        for (int nt = 0; nt < NT; nt++) {
            short8 b = *((const short8*)&Ws[nt * 16 + m][kc + quad * 8]);
            acc[nt] = __builtin_amdgcn_mfma_f32_16x16x32_bf16(a, b, acc[nt], 0, 0, 0);
        }
    }

    __syncthreads();
    if (OUTFP8) {
        uchar8* c8lds = (uchar8*)&As[0][0];
#pragma unroll
        for (int nt = 0; nt < NT; nt++)
#pragma unroll
            for (int r = 0; r < 4; r++)
                c8lds[(wave * 16 + quad * 4 + r) * N + nt * 16 + m] = f2fp8(acc[nt][r]);
        __syncthreads();
#pragma unroll
        for (int p = 0; p < 64 * N / 16 / 256; p++) {
            int u = tid + 256 * p;
            int row = u / (N / 16), c16 = u % (N / 16);
            int gr = blockRow + row;
            if (gr < M)
                ((uint4*)Cout)[gr * (N / 16) + c16] = *((const uint4*)&c8lds[row * N + c16 * 16]);
        }
    } else {
#pragma unroll
        for (int nt = 0; nt < NT; nt++)
#pragma unroll
            for (int r = 0; r < 4; r++)
                As[wave * 16 + quad * 4 + r][nt * 16 + m] = f2bf(acc[nt][r]);
        __syncthreads();
#pragma unroll
        for (int p = 0; p < 64 * N / 8 / 256; p++) {
            int u = tid + 256 * p;
            int row = u / (N / 8), c8 = u % (N / 8);
            int gr = blockRow + row;
            if (gr < M)
                ((uint4*)Cout)[gr * (N / 8) + c8] = *((const uint4*)&As[row][c8 * 8]);
        }
    }
}

// ---- One-pass bucket scatter: edges -> ebuf[bucket][slot], fixed stride -----
// Packed edge: [w:f16 bits 47..32][fine:20..16][src:15..0]
__global__ __launch_bounds__(1024) void scatter_kernel(const int* __restrict__ ei,
                                                       const float* __restrict__ ew,
                                                       int* __restrict__ cursor,
                                                       u64* __restrict__ ebuf) {
    __shared__ int hist[NB];
    __shared__ int lbase[NB];
    int t = threadIdx.x, blk = blockIdx.x;
    for (int i = t; i < NB; i += 1024) hist[i] = 0;
    __syncthreads();

    int base = blk * EPB;
    int  myb[EPB / 1024];
    u64  myv[EPB / 1024];
    bool ok[EPB / 1024];
#pragma unroll
    for (int k = 0; k < EPB / 1024; k++) {
        int e = base + t + k * 1024;
        ok[k] = (e < N_EDGES);
        if (ok[k]) {
            int dst = ei[N_EDGES + e];
            int src = ei[e];
            float w = ew[e];
            int b = dst >> BSH;
            myb[k] = b;
            myv[k] = ((u64)f2h_bits(w) << 32) | ((uint32)(dst & (BSZ - 1)) << 16) | (uint32)src;
            atomicAdd(&hist[b], 1);
        }
    }
    __syncthreads();
    for (int i = t; i < NB; i += 1024) {
        int n = hist[i];
        lbase[i] = n ? atomicAdd(&cursor[i], n) : 0;
    }
    __syncthreads();
    for (int i = t; i < NB; i += 1024) hist[i] = 0;   // reuse as in-block rank cursor
    __syncthreads();
#pragma unroll
    for (int k = 0; k < EPB / 1024; k++) {
        if (ok[k]) {
            int b = myb[k];
            int r = atomicAdd(&hist[b], 1);
            int pos = lbase[b] + r;
            if (pos < CAPB)
                ebuf[(size_t)b * CAPB + pos] = myv[k];
        }
    }
}

// ---- agg1: A1 = relu(bucket-LDS segment_sum(w * H1[src]) + b1), bf16 out ----
__global__ __launch_bounds__(256) void agg1_kernel(const uint32* __restrict__ H1,
                                                   const int* __restrict__ cursor,
                                                   const u64* __restrict__ ebuf,
                                                   const float* __restrict__ b1,
                                                   uint32* __restrict__ A1) {
    __shared__ float acc[BSZ][128];
    int b = blockIdx.x;
    int t = threadIdx.x, wave = t >> 6, lane = t & 63;
    for (int i = t; i < BSZ * 128; i += 256) ((float*)acc)[i] = 0.f;
    __syncthreads();

    int cnt = cursor[b]; if (cnt > CAPB) cnt = CAPB;
    const u64* eb = ebuf + (size_t)b * CAPB;
    int s0 = (cnt * wave) >> 2, s1 = (cnt * (wave + 1)) >> 2;
    int i = s0;
    for (; i + 4 <= s1; i += 4) {
        u64 v[4];
#pragma unroll
        for (int j = 0; j < 4; j++) v[j] = eb[i + j];
        uint32 h[4];
#pragma unroll
        for (int j = 0; j < 4; j++) h[j] = H1[(int)(v[j] & 0xFFFFu) * 64 + lane];
#pragma unroll
        for (int j = 0; j < 4; j++) {
            int   f = (int)((v[j] >> 16) & (BSZ - 1));
            float w = h_bits2f((uint32)(v[j] >> 32) & 0xFFFFu);
            atomicAdd(&acc[f][2 * lane],     w * bf_lo(h[j]));
            atomicAdd(&acc[f][2 * lane + 1], w * bf_hi(h[j]));
        }
    }
    for (; i < s1; i++) {
        u64 v = eb[i];
        uint32 h = H1[(int)(v & 0xFFFFu) * 64 + lane];
        int   f = (int)((v >> 16) & (BSZ - 1));
        float w = h_bits2f((uint32)(v >> 32) & 0xFFFFu);
        atomicAdd(&acc[f][2 * lane],     w * bf_lo(h));
        atomicAdd(&acc[f][2 * lane + 1], w * bf_hi(h));
    }
    __syncthreads();

    int node0 = b * BSZ;
    const float2* b1v = (const float2*)b1;
    for (int u = t; u < BSZ * 64; u += 256) {
        int r = u >> 6, c = u & 63;
        int node = node0 + r;
        if (node < N_NODES) {
            float2 bb = b1v[c];
            float v0 = fmaxf(acc[r][2 * c]     + bb.x, 0.f);
            float v1 = fmaxf(acc[r][2 * c + 1] + bb.y, 0.f);
            A1[node * 64 + c] = (uint32)f2bf(v0) | ((uint32)f2bf(v1) << 16);
        }
    }
}

// ---- agg2: out(fp32) = bucket-LDS segment_sum(H2[src]) + b2; H2 fp8 ---------
__global__ __launch_bounds__(256) void agg2_kernel(const uchar8* __restrict__ H2,
                                                   const int* __restrict__ cursor,
                                                   const u64* __restrict__ ebuf,
                                                   const float* __restrict__ b2,
                                                   float* __restrict__ out) {
    __shared__ float acc[BSZ][64];
    int b = blockIdx.x;
    int t = threadIdx.x, wave = t >> 6, lane = t & 63;
    for (int i = t; i < BSZ * 64; i += 256) ((float*)acc)[i] = 0.f;
    __syncthreads();

    int cnt = cursor[b]; if (cnt > CAPB) cnt = CAPB;
    const u64* eb = ebuf + (size_t)b * CAPB;
    int s0 = (cnt * wave) >> 2, s1 = (cnt * (wave + 1)) >> 2;
    int i = s0;
    for (; i + 8 <= s1; i += 8) {
        u64 v[8];
#pragma unroll
        for (int j = 0; j < 8; j++) v[j] = eb[i + j];
        uchar8 hb[8];
#pragma unroll
        for (int j = 0; j < 8; j++) hb[j] = H2[(int)(v[j] & 0xFFFFu) * 64 + lane];
#pragma unroll
        for (int j = 0; j < 8; j++) {
            int f = (int)((v[j] >> 16) & (BSZ - 1));
            atomicAdd(&acc[f][lane], fp82f(hb[j]));
        }
    }
    for (; i < s1; i++) {
        u64 v = eb[i];
        uchar8 hb = H2[(int)(v & 0xFFFFu) * 64 + lane];
        int f = (int)((v >> 16) & (BSZ - 1));
        atomicAdd(&acc[f][lane], fp82f(hb));
    }
    __syncthreads();

    int node0 = b * BSZ;
    for (int u = t; u < BSZ * 64; u += 256) {
        int r = u >> 6, c = u & 63;
        int node = node0 + r;
        if (node < N_NODES)
            out[node * 64 + c] = acc[r][c] + b2[c];
    }
}

// ---------------- launch -----------------------------------------------------
extern "C" void kernel_launch(void* const* d_in, const int* in_sizes, int n_in,
                              void* d_out, int out_size, void* d_ws, size_t ws_size,
                              hipStream_t stream) {
    const float* x  = (const float*)d_in[0];
    const int*   ei = (const int*)  d_in[1];   // [2, E] int32
    const float* ew = (const float*)d_in[2];
    const float* W1 = (const float*)d_in[3];
    const float* b1 = (const float*)d_in[4];
    const float* W2 = (const float*)d_in[5];
    const float* b2 = (const float*)d_in[6];
    float* out = (float*)d_out;

    // workspace layout (u32 units)
    uint32* H1      = (uint32*)d_ws;                   // 50000*64  (bf16 [N][128])
    uint32* A1      = H1 + (size_t)N_NODES * 64;       // 50000*64  (bf16 [N][128])
    uint32* H2      = A1 + (size_t)N_NODES * 64;       // 50000*16  (fp8 [N][64])
    ushort16* W1t   = (ushort16*)(H2 + (size_t)N_NODES * 16);  // 128*128 bf16
    ushort16* W2t   = W1t + 128 * 128;                 // 64*128 bf16
    int* cursor     = (int*)(W2t + 64 * 128);          // NB (+1 pad for 8B align)
    u64* ebuf       = (u64*)(cursor + ((NB + 1) & ~1)); // NB*CAPB packed edges

    const int gemmBlocks = (N_NODES + 63) / 64;     // 782

    // W transposes (bf16) + zero bucket cursors
    prep_w_kernel<<<96, 256, 0, stream>>>(W1, W2, W1t, W2t, cursor);

    // H1(bf16) = x @ W1   [MFMA]
    mfma_gemm_kernel<8, false, false><<<gemmBlocks, 256, 0, stream>>>(x, W1t, H1, N_NODES);

    // one-pass bucket scatter (32-node buckets, fixed stride, no scan/fine sort)
    scatter_kernel<<<NBLK, 1024, 0, stream>>>(ei, ew, cursor, ebuf);

    // A1(bf16) = relu(segment_sum(w * H1[src]) + b1)   [LDS accumulators]
    agg1_kernel<<<NB, 256, 0, stream>>>(H1, cursor, ebuf, b1, A1);

    // H2(fp8) = A1 @ W2   [MFMA, bf16 A, fp8 out]
    mfma_gemm_kernel<4, true, true><<<gemmBlocks, 256, 0, stream>>>(A1, W2t, H2, N_NODES);

    // out = segment_sum(H2[src]) + b2   [LDS accumulators]
    agg2_kernel<<<NB, 256, 0, stream>>>((const uchar8*)H2, cursor, ebuf, b2, out);
}

// Round 2
// 183.190 us; speedup vs baseline: 5.5098x; 5.5098x over previous
//
#include <hip/hip_runtime.h>
#include <hip/hip_fp8.h>

#define N_NODES 50000
#define N_EDGES 800000
#define IN_C    128
#define HID_C   128
#define OUT_C   64

#define EPB     4096            // edges per scatter block
#define NBLK    196             // ceil(N_EDGES / EPB)
#define NBUCKET 196             // ceil(N_NODES / 256)
#define CAP     6144            // max edges per coarse bucket (mean 4096, sigma 64 -> +32 sigma)

typedef unsigned int   uint32;
typedef unsigned short ushort16;
typedef unsigned char  uchar8;
typedef __attribute__((ext_vector_type(8))) short short8;
typedef __attribute__((ext_vector_type(4))) float f32x4;

__device__ __forceinline__ ushort16 f2bf(float f) {
    uint32 u = __float_as_uint(f);
    u += 0x7FFFu + ((u >> 16) & 1u);        // RNE
    return (ushort16)(u >> 16);
}
__device__ __forceinline__ float bf_lo(uint32 h) { return __uint_as_float(h << 16); }
__device__ __forceinline__ float bf_hi(uint32 h) { return __uint_as_float(h & 0xFFFF0000u); }

__device__ __forceinline__ ushort16 f2h_bits(float f) {
    union { _Float16 h; ushort16 u; } cv;
    cv.h = (_Float16)f;
    return cv.u;
}
__device__ __forceinline__ float h_bits2f(uint32 bits) {
    union { ushort16 u; _Float16 h; } cv;
    cv.u = (ushort16)bits;
    return (float)cv.h;
}
__device__ __forceinline__ uchar8 f2fp8(float f) {
    __hip_fp8_e4m3 t(f);                    // OCP e4m3fn, RNE-saturating
    return *reinterpret_cast<unsigned char*>(&t);
}
__device__ __forceinline__ float fp82f(uchar8 b) {
    __hip_fp8_e4m3 t;
    *reinterpret_cast<unsigned char*>(&t) = b;
    return (float)t;
}

// ---- W pre-transpose (bf16) + coarse-bucket cursor zeroing ------------------
__global__ void prep_w_kernel(const float* __restrict__ W1, const float* __restrict__ W2,
                              ushort16* __restrict__ W1t, ushort16* __restrict__ W2t,
                              int* __restrict__ cursorC) {
    if (blockIdx.x == 0 && threadIdx.x < NBUCKET) cursorC[threadIdx.x] = 0;
    int i = blockIdx.x * 256 + threadIdx.x;
    if (i < 128 * 128) {
        int n = i / 128, k = i % 128;
        W1t[i] = f2bf(W1[k * 128 + n]);
    }
    int j = i - 128 * 128;
    if (j >= 0 && j < 64 * 128) {
        int n = j / 128, k = j % 128;
        W2t[j] = f2bf(W2[k * 64 + n]);
    }
}

// ---------------- MFMA GEMM: C[M,N] = A[M,128] * W[128,N] --------------------
// Output: bf16 (OUTFP8=false) or fp8 e4m3 (true).
template<int NT, bool ABF16, bool OUTFP8>
__global__ __launch_bounds__(256) void mfma_gemm_kernel(const void* __restrict__ Aptr,
                                                        const ushort16* __restrict__ Wt,
                                                        void* __restrict__ Cout, int M) {
    constexpr int N = NT * 16;
    __shared__ ushort16 As[64][136];       // +8 pad breaks 16-way bank aliasing
    __shared__ ushort16 Ws[N][136];

    const int tid  = threadIdx.x;
    const int wave = tid >> 6;
    const int lane = tid & 63;
    const int quad = lane >> 4;
    const int m    = lane & 15;
    const int blockRow = blockIdx.x * 64;

#pragma unroll
    for (int p = 0; p < N * 16 / 256; p++) {
        int u = tid + 256 * p;
        int row = u / 16, c8 = u % 16;
        uint4 v = ((const uint4*)Wt)[u];
        *((uint4*)&Ws[row][c8 * 8]) = v;
    }
    if (ABF16) {
#pragma unroll
        for (int p = 0; p < 4; p++) {
            int u = tid + 256 * p;
            int row = u / 16, c8 = u % 16;
            int gr = blockRow + row; if (gr > M - 1) gr = M - 1;
            uint4 v = ((const uint4*)Aptr)[gr * 16 + c8];
            *((uint4*)&As[row][c8 * 8]) = v;
        }
    } else {
#pragma unroll
        for (int p = 0; p < 8; p++) {
            int u = tid + 256 * p;
            int row = u / 32, c4 = u % 32;
            int gr = blockRow + row; if (gr > M - 1) gr = M - 1;
            float4 v = ((const float4*)Aptr)[gr * 32 + c4];
            ushort4 s;
            s.x = f2bf(v.x); s.y = f2bf(v.y); s.z = f2bf(v.z); s.w = f2bf(v.w);
            *((ushort4*)&As[row][c4 * 4]) = s;
        }
    }
    __syncthreads();

    f32x4 acc[NT];
#pragma unroll
    for (int nt = 0; nt < NT; nt++) acc[nt] = (f32x4){0.f, 0.f, 0.f, 0.f};

#pragma unroll
    for (int kc = 0; kc < 128; kc += 32) {
        short8 a = *((const short8*)&As[wave * 16 + m][kc + quad * 8]);
#pragma unroll
        for (int nt = 0; nt < NT; nt++) {
            short8 b = *((const short8*)&Ws[nt * 16 + m][kc + quad * 8]);
            acc[nt] = __builtin_amdgcn_mfma_f32_16x16x32_bf16(a, b, acc[nt], 0, 0, 0);
        }
    }

    __syncthreads();
    if (OUTFP8) {
        // regs -> LDS (fp8 bytes) -> coalesced 16B stores; row stride N bytes
        uchar8* c8lds = (uchar8*)&As[0][0];
#pragma unroll
        for (int nt = 0; nt < NT; nt++)
#pragma unroll
            for (int r = 0; r < 4; r++)
                c8lds[(wave * 16 + quad * 4 + r) * N + nt * 16 + m] = f2fp8(acc[nt][r]);
        __syncthreads();
#pragma unroll
        for (int p = 0; p < 64 * N / 16 / 256; p++) {
            int u = tid + 256 * p;
            int row = u / (N / 16), c16 = u % (N / 16);
            int gr = blockRow + row;
            if (gr < M)
                ((uint4*)Cout)[gr * (N / 16) + c16] = *((const uint4*)&c8lds[row * N + c16 * 16]);
        }
    } else {
#pragma unroll
        for (int nt = 0; nt < NT; nt++)
#pragma unroll
            for (int r = 0; r < 4; r++)
                As[wave * 16 + quad * 4 + r][nt * 16 + m] = f2bf(acc[nt][r]);
        __syncthreads();
#pragma unroll
        for (int p = 0; p < 64 * N / 8 / 256; p++) {
            int u = tid + 256 * p;
            int row = u / (N / 8), c8 = u % (N / 8);
            int gr = blockRow + row;
            if (gr < M)
                ((uint4*)Cout)[gr * (N / 8) + c8] = *((const uint4*)&As[row][c8 * 8]);
        }
    }
}

// ---- Fused coarse scatter: count (LDS int atomics) -> one global atomicAdd
// per (block,bucket) -> scatter into fixed-stride bucket regions. Replaces
// csr_count + csr_scan + csr_scatter1: edges read ONCE, no global scan.
__global__ __launch_bounds__(1024) void scatter_coarse_kernel(const int* __restrict__ ei,
                                                              const float* __restrict__ ew,
                                                              int* __restrict__ cursorC,
                                                              uint32* __restrict__ key32,
                                                              ushort16* __restrict__ wH) {
    __shared__ int hist[256];
    __shared__ int lbase[256];
    int t = threadIdx.x, blk = blockIdx.x;
    if (t < 256) hist[t] = 0;
    __syncthreads();

    int base = blk * EPB;
    int    bk[EPB / 1024];
    uint32 pk[EPB / 1024];
    ushort16 wb[EPB / 1024];
    bool   ok[EPB / 1024];
#pragma unroll
    for (int k = 0; k < EPB / 1024; k++) {
        int e = base + t + k * 1024;
        ok[k] = (e < N_EDGES);
        if (ok[k]) {
            int dst = ei[N_EDGES + e];
            int src = ei[e];
            float w = ew[e];
            bk[k] = dst >> 8;
            pk[k] = ((uint32)(dst & 255) << 16) | (uint32)src;
            wb[k] = f2h_bits(w);
            atomicAdd(&hist[bk[k]], 1);           // LDS int atomic (native)
        }
    }
    __syncthreads();
    if (t < 256) {
        int n = hist[t];
        lbase[t] = n ? atomicAdd(&cursorC[t], n) : 0;   // one global atomic per (blk,bucket)
        hist[t] = 0;                                     // reuse as in-block rank cursor
    }
    __syncthreads();
#pragma unroll
    for (int k = 0; k < EPB / 1024; k++) {
        if (ok[k]) {
            int b = bk[k];
            int r = atomicAdd(&hist[b], 1);       // LDS int atomic
            int pos = lbase[b] + r;
            if (pos < CAP) {
                int slot = b * CAP + pos;
                key32[slot] = pk[k];
                wH[slot]    = wb[k];
            }
        }
    }
}

// ---- Fine sort within each coarse bucket (fixed-stride region b*CAP) --------
__global__ __launch_bounds__(1024) void csr_fine_kernel(const uint32* __restrict__ key32,
                                                        const ushort16* __restrict__ wH,
                                                        const int* __restrict__ cursorC,
                                                        int* __restrict__ rowStart,
                                                        int* __restrict__ rowEnd,
                                                        uint32* __restrict__ pairs) {
    __shared__ uint32   keys[CAP];
    __shared__ ushort16 ws[CAP];
    __shared__ int hist[256];
    __shared__ int scan[256];
    int b = blockIdx.x, t = threadIdx.x;
    int s = b * CAP;
    int len = cursorC[b];
    if (len > CAP) len = CAP;
    if (t < 256) hist[t] = 0;
    __syncthreads();
    for (int j = t; j < len; j += 1024) {
        uint32 kv = key32[s + j];
        keys[j] = kv;
        ws[j]   = wH[s + j];
        atomicAdd(&hist[kv >> 16], 1);   // LDS atomic
    }
    __syncthreads();
    if (t < 256) scan[t] = hist[t];
    __syncthreads();
    for (int off = 1; off < 256; off <<= 1) {
        int a = 0;
        if (t < 256 && t >= off) a = scan[t - off];
        __syncthreads();
        if (t < 256) scan[t] += a;
        __syncthreads();
    }
    if (t < 256) {
        int excl = scan[t] - hist[t];
        hist[t] = excl;
        int node = b * 256 + t;
        if (node < N_NODES) {
            rowStart[node] = s + excl;
            rowEnd[node]   = s + scan[t];
        }
    }
    __syncthreads();
    for (int j = t; j < len; j += 1024) {
        uint32 kv = keys[j];
        int r = atomicAdd(&hist[kv >> 16], 1);   // LDS atomic
        pairs[s + r] = (kv & 0xFFFFu) | ((uint32)ws[j] << 16);
    }
}

// ---------------- Aggregations (wave = node, full-row gather) ----------------
__global__ __launch_bounds__(256) void agg1_kernel(const uint32* __restrict__ H1,
                                                   const int* __restrict__ rowStart,
                                                   const int* __restrict__ rowEnd,
                                                   const uint32* __restrict__ pairs,
                                                   const float* __restrict__ b1,
                                                   uint32* __restrict__ A1) {
    int node = blockIdx.x * 4 + (threadIdx.x >> 6);
    int lane = threadIdx.x & 63;
    if (node >= N_NODES) return;
    int s = rowStart[node], e = rowEnd[node];
    float2 acc = ((const float2*)b1)[lane];
    int i = s;
    for (; i + 8 <= e; i += 8) {
        uint32 p[8], h[8];
#pragma unroll
        for (int j = 0; j < 8; j++) p[j] = pairs[i + j];
#pragma unroll
        for (int j = 0; j < 8; j++) h[j] = H1[(p[j] & 0xFFFFu) * 64 + lane];
#pragma unroll
        for (int j = 0; j < 8; j++) {
            float w = h_bits2f(p[j] >> 16);
            acc.x += w * bf_lo(h[j]);
            acc.y += w * bf_hi(h[j]);
        }
    }
    for (; i < e; i++) {
        uint32 p = pairs[i];
        uint32 h = H1[(p & 0xFFFFu) * 64 + lane];
        float  w = h_bits2f(p >> 16);
        acc.x += w * bf_lo(h);
        acc.y += w * bf_hi(h);
    }
    float rx = fmaxf(acc.x, 0.f), ry = fmaxf(acc.y, 0.f);
    A1[node * 64 + lane] = (uint32)f2bf(rx) | ((uint32)f2bf(ry) << 16);
}

// agg2: out[i](fp32) = b2 + sum_e H2[src_e]; H2 fp8 e4m3, 64 B/row (L2-resident)
__global__ __launch_bounds__(256) void agg2_kernel(const uchar8* __restrict__ H2,
                                                   const int* __restrict__ rowStart,
                                                   const int* __restrict__ rowEnd,
                                                   const uint32* __restrict__ pairs,
                                                   const float* __restrict__ b2,
                                                   float* __restrict__ out) {
    int node = blockIdx.x * 4 + (threadIdx.x >> 6);
    int lane = threadIdx.x & 63;
    if (node >= N_NODES) return;
    int s = rowStart[node], e = rowEnd[node];
    float acc = b2[lane];
    int i = s;
    for (; i + 8 <= e; i += 8) {
        uchar8 v[8];
#pragma unroll
        for (int j = 0; j < 8; j++) v[j] = H2[(pairs[i + j] & 0xFFFFu) * 64 + lane];
#pragma unroll
        for (int j = 0; j < 8; j++) acc += fp82f(v[j]);
    }
    for (; i < e; i++)
        acc += fp82f(H2[(pairs[i] & 0xFFFFu) * 64 + lane]);
    out[node * 64 + lane] = acc;
}

// ---------------- launch -----------------------------------------------------
extern "C" void kernel_launch(void* const* d_in, const int* in_sizes, int n_in,
                              void* d_out, int out_size, void* d_ws, size_t ws_size,
                              hipStream_t stream) {
    const float* x  = (const float*)d_in[0];
    const int*   ei = (const int*)  d_in[1];   // [2, E] int32
    const float* ew = (const float*)d_in[2];
    const float* W1 = (const float*)d_in[3];
    const float* b1 = (const float*)d_in[4];
    const float* W2 = (const float*)d_in[5];
    const float* b2 = (const float*)d_in[6];
    float* out = (float*)d_out;

    // workspace layout (u32 units)
    uint32* H1      = (uint32*)d_ws;                   // 50000*64  (bf16 [N][128])
    uint32* A1      = H1 + (size_t)N_NODES * 64;       // 50000*64  (bf16 [N][128])
    uint32* H2      = A1 + (size_t)N_NODES * 64;       // 50000*16  (fp8 [N][64])
    uint32* pairs   = H2 + (size_t)N_NODES * 16;       // NBUCKET*CAP (src u16 | f16 w)
    uint32* key32   = pairs + (size_t)NBUCKET * CAP;   // NBUCKET*CAP (fine<<16 | src)
    ushort16* wH    = (ushort16*)(key32 + (size_t)NBUCKET * CAP);  // NBUCKET*CAP u16
    ushort16* W1t   = wH + (size_t)NBUCKET * CAP + (((size_t)NBUCKET * CAP) & 1);
    ushort16* W2t   = W1t + 128 * 128;                 // 64*128 bf16 transposed
    int* cursorC    = (int*)(W2t + 64 * 128);          // NBUCKET
    int* rowStart   = cursorC + ((NBUCKET + 1) & ~1);  // 50000
    int* rowEnd     = rowStart + N_NODES;              // 50000

    const int gemmBlocks = (N_NODES + 63) / 64;     // 782
    const int nodeBlocks = (N_NODES + 3) / 4;       // 12500

    // W transposes (bf16) + zero coarse cursors
    prep_w_kernel<<<96, 256, 0, stream>>>(W1, W2, W1t, W2t, cursorC);

    // H1(bf16) = x @ W1   [MFMA]
    mfma_gemm_kernel<8, false, false><<<gemmBlocks, 256, 0, stream>>>(x, W1t, H1, N_NODES);

    // fused CSR coarse pass: count + global-base + scatter (edges read once)
    scatter_coarse_kernel<<<NBLK, 1024, 0, stream>>>(ei, ew, cursorC, key32, wH);

    // fine sort to node granularity within each bucket region
    csr_fine_kernel<<<NBUCKET, 1024, 0, stream>>>(key32, wH, cursorC, rowStart, rowEnd, pairs);

    // A1(bf16) = relu(segment_sum(w * H1[src]) + b1)
    agg1_kernel<<<nodeBlocks, 256, 0, stream>>>(H1, rowStart, rowEnd, pairs, b1, A1);

    // H2(fp8) = A1 @ W2   [MFMA, bf16 A, fp8 out]
    mfma_gemm_kernel<4, true, true><<<gemmBlocks, 256, 0, stream>>>(A1, W2t, H2, N_NODES);

    // out = segment_sum(H2[src]) + b2
    agg2_kernel<<<nodeBlocks, 256, 0, stream>>>((const uchar8*)H2, rowStart, rowEnd, pairs, b2, out);
}